// Round 9
// baseline (444.288 us; speedup 1.0000x reference)
//
#include <hip/hip_runtime.h>
#include <hip/hip_bf16.h>
#include <cstdint>

#define ASPACE(n) __attribute__((address_space(n)))

typedef short bf16x8 __attribute__((ext_vector_type(8)));
typedef float f32x4 __attribute__((ext_vector_type(4)));

__device__ __forceinline__ unsigned short f2bf(float f) {
  uint32_t u = __float_as_uint(f);
  u += 0x7fffu + ((u >> 16) & 1u);
  return (unsigned short)(u >> 16);
}
__device__ __forceinline__ float bf2f(unsigned short h) {
  return __uint_as_float(((uint32_t)h) << 16);
}

// ---------------- fp32 -> bf16 conversion ----------------
__global__ __launch_bounds__(256) void conv_f32_bf16(const float4* __restrict__ src,
                                                     ushort4* __restrict__ dst, int n4) {
  int i = blockIdx.x * blockDim.x + threadIdx.x;
  int stride = gridDim.x * blockDim.x;
  for (; i < n4; i += stride) {
    float4 v = src[i];
    ushort4 o;
    o.x = f2bf(v.x); o.y = f2bf(v.y); o.z = f2bf(v.z); o.w = f2bf(v.w);
    dst[i] = o;
  }
}

// ---------------- bf16 GEMM (B^T input): C[m,n] = sum_k A[m,k]*B[n,k] ----------------
// BM=128, BN=192, BK=32. 256 threads (4 waves as 2x2; per-wave 64x96, acc[4][6]).
// T4 DEEP: 4 LDS buffers (80 KiB -> 2 blocks/CU), 3-tiles-ahead prefetch, raw s_barrier
// with counted vmcnt(10) -- tile t's loads were issued 3 iterations (~700-800 cyc)
// earlier, covering the ~900-cyc HBM cold-miss latency of streamed A.
// Tile i -> buf i&3. Swizzle chunk ^= (row>>1)&3 both sides (0 conflicts, r4/r7/r8).
// Addresses hoisted (r7: VALUBusy 46->23%).

__device__ __forceinline__ void gload16(const unsigned short* g, unsigned short* l) {
  __builtin_amdgcn_global_load_lds((const ASPACE(1) void*)g, (ASPACE(3) void*)l, 16, 0, 0);
}

template <int OUT_MODE>   // 0: bf16 out, no bias; 1: fp32 out + bias
__global__ __launch_bounds__(256, 2) void gemm_bt(const unsigned short* __restrict__ A,
                                                  const unsigned short* __restrict__ B,
                                                  void* __restrict__ Cout,
                                                  const float* __restrict__ bias,
                                                  int M, int N, int K) {
  __shared__ unsigned short As[4][128 * 32];   // 32 KiB
  __shared__ unsigned short Bs[4][192 * 32];   // 48 KiB

  const int tid  = threadIdx.x;
  const int lane = tid & 63;
  const int wave = tid >> 6;
  const int wr = wave >> 1;        // 0..1 -> 64-row band
  const int wc = wave & 1;         // 0..1 -> 96-col band

  // 1D grid: XCD-chunked (nwg % 8 == 0), N-tile fastest for A L2-reuse
  const int nwg = gridDim.x;
  const int swz = (blockIdx.x & 7) * (nwg >> 3) + (blockIdx.x >> 3);
  const int ntn = N / 192;
  const int bn0 = (swz % ntn) * 192;
  const int bm0 = (swz / ntn) << 7;

  const unsigned short* Abase = A + (size_t)bm0 * K;
  const unsigned short* Bbase = B + (size_t)bn0 * K;

  // hoisted staging addresses: chunk c -> row c>>2, phys chunk c&3, global col-chunk
  // (c&3)^((row>>1)&3); LDS dest is linear (wave-uniform base + lane*16).
  const unsigned short* gA[2];
  const unsigned short* gB[3];
  unsigned short* lA[2];
  unsigned short* lB[3];
#pragma unroll
  for (int i = 0; i < 2; ++i) {
    const int c = i * 256 + tid;
    const int r = c >> 2;
    const int gc = (c & 3) ^ ((r >> 1) & 3);
    gA[i] = Abase + (size_t)r * K + gc * 8;
    lA[i] = (unsigned short*)As + (i * 256 + wave * 64) * 8;
  }
#pragma unroll
  for (int i = 0; i < 3; ++i) {
    const int c = i * 256 + tid;
    const int r = c >> 2;
    const int gc = (c & 3) ^ ((r >> 1) & 3);
    gB[i] = Bbase + (size_t)r * K + gc * 8;
    lB[i] = (unsigned short*)Bs + (i * 256 + wave * 64) * 8;
  }
  const int abufoff = 128 * 32;   // shorts per A buffer
  const int bbufoff = 192 * 32;

  // hoisted fragment LDS offsets (shorts)
  const int fr = lane & 15;
  const int hi = lane >> 4;
  int afo[4], bfo[6];
#pragma unroll
  for (int m = 0; m < 4; ++m) {
    const int row = wr * 64 + m * 16 + fr;
    afo[m] = row * 32 + ((hi ^ ((row >> 1) & 3)) * 8);
  }
#pragma unroll
  for (int n = 0; n < 6; ++n) {
    const int row = wc * 96 + n * 16 + fr;
    bfo[n] = row * 32 + ((hi ^ ((row >> 1) & 3)) * 8);
  }

  f32x4 acc[4][6];
#pragma unroll
  for (int m = 0; m < 4; ++m)
#pragma unroll
    for (int n = 0; n < 6; ++n) {
      f32x4 z = {0.f, 0.f, 0.f, 0.f};
      acc[m][n] = z;
    }

  const int NT = K >> 5;          // 12 for K=384

  // prologue: stage tiles 0,1,2 into bufs 0,1,2 (15 loads/thread outstanding)
#pragma unroll
  for (int tt = 0; tt < 3; ++tt) {
#pragma unroll
    for (int i = 0; i < 2; ++i) gload16(gA[i] + (tt << 5), lA[i] + tt * abufoff);
#pragma unroll
    for (int i = 0; i < 3; ++i) gload16(gB[i] + (tt << 5), lB[i] + tt * bbufoff);
  }

  for (int t = 0; t < NT; ++t) {
    // wait tile t's 5 loads; keep later tiles' loads in flight (T4 counted vmcnt)
    const int rem = NT - t;       // tiles t.. in flight: min(3, rem)
    if (rem >= 3)      asm volatile("s_waitcnt vmcnt(10)" ::: "memory");
    else if (rem == 2) asm volatile("s_waitcnt vmcnt(5)"  ::: "memory");
    else               asm volatile("s_waitcnt vmcnt(0)"  ::: "memory");
    __builtin_amdgcn_s_barrier();   // raw barrier: no compiler vmcnt(0) drain
    __builtin_amdgcn_sched_barrier(0);

    if (t + 3 < NT) {               // stage tile t+3 into buf (t+3)&3 (read at iter t-1)
      const int k0 = (t + 3) << 5;
      const int nb = (t + 3) & 3;
#pragma unroll
      for (int i = 0; i < 2; ++i) gload16(gA[i] + k0, lA[i] + nb * abufoff);
#pragma unroll
      for (int i = 0; i < 3; ++i) gload16(gB[i] + k0, lB[i] + nb * bbufoff);
    }
    __builtin_amdgcn_sched_barrier(0);

    // compute tile t from buf[t&3] (compiler inserts lgkm waits for ds_read->MFMA)
    {
      const int cb = t & 3;
      const unsigned short* Ab = (const unsigned short*)As + cb * abufoff;
      const unsigned short* Bb = (const unsigned short*)Bs + cb * bbufoff;
      bf16x8 af[4], bfv[6];
#pragma unroll
      for (int m = 0; m < 4; ++m) af[m] = *(const bf16x8*)(Ab + afo[m]);
#pragma unroll
      for (int n = 0; n < 6; ++n) bfv[n] = *(const bf16x8*)(Bb + bfo[n]);
#pragma unroll
      for (int m = 0; m < 4; ++m)
#pragma unroll
        for (int n = 0; n < 6; ++n)
          acc[m][n] = __builtin_amdgcn_mfma_f32_16x16x32_bf16(af[m], bfv[n], acc[m][n], 0, 0, 0);
    }
  }

  // epilogue: C/D layout col = lane&15, row = (lane>>4)*4 + reg   [guide-verified m89/m91]
  const int rq = hi * 4;
  if (OUT_MODE == 1) {
    float* C = (float*)Cout;
#pragma unroll
    for (int m = 0; m < 4; ++m) {
#pragma unroll
      for (int n = 0; n < 6; ++n) {
        const int col = bn0 + wc * 96 + n * 16 + fr;
        const float bv = bias[col];
#pragma unroll
        for (int r = 0; r < 4; ++r) {
          const int row = bm0 + wr * 64 + m * 16 + rq + r;
          C[(size_t)row * N + col] = acc[m][n][r] + bv;
        }
      }
    }
  } else {
    unsigned short* C = (unsigned short*)Cout;
#pragma unroll
    for (int m = 0; m < 4; ++m) {
#pragma unroll
      for (int n = 0; n < 6; ++n) {
        const int col = bn0 + wc * 96 + n * 16 + fr;
#pragma unroll
        for (int r = 0; r < 4; ++r) {
          const int row = bm0 + wr * 64 + m * 16 + rq + r;
          C[(size_t)row * N + col] = f2bf(acc[m][n][r]);
        }
      }
    }
  }
}

// ---------------- windowed attention (MFMA, one wave per (b,h,window)) ----------------
#define PADV 24
#define PADP 24
__global__ __launch_bounds__(256) void win_attn(const unsigned short* __restrict__ qkv,
                                                unsigned short* __restrict__ aout) {
  __shared__ unsigned short lds[4][48 * PADV + 16 * PADP];
  const int tid = threadIdx.x;
  const int wave = tid >> 6, lane = tid & 63;
  const int wg = blockIdx.x * 4 + wave;     // ((b*1024 + w)*8 + h)
  const int h = wg & 7;
  const int bw = wg >> 3;
  const int w = bw & 1023, b = bw >> 10;
  const int wy = w >> 5, wx = w & 31;

  unsigned short* Vt = lds[wave];
  unsigned short* P  = lds[wave] + 48 * PADV;

  const int lg = lane >> 4;
  const int lr = lane & 15;

  const int n_lr = (wy * 4 + (lr >> 2)) * 128 + wx * 4 + (lr & 3);
  const size_t rowbase = ((size_t)(b * 16384 + n_lr)) * 1152 + h * 48;

  bf16x8 aq0, bk0;
  bf16x8 aq1 = {0, 0, 0, 0, 0, 0, 0, 0};
  bf16x8 bk1 = {0, 0, 0, 0, 0, 0, 0, 0};
  aq0 = *(const bf16x8*)(qkv + rowbase + lg * 8);
  bk0 = *(const bf16x8*)(qkv + rowbase + 384 + lg * 8);
  if (lg < 2) {
    aq1 = *(const bf16x8*)(qkv + rowbase + 32 + lg * 8);
    bk1 = *(const bf16x8*)(qkv + rowbase + 384 + 32 + lg * 8);
  }

  {
    bf16x8 v = *(const bf16x8*)(qkv + rowbase + 768 + lg * 8);
#pragma unroll
    for (int i = 0; i < 8; ++i) Vt[(lg * 8 + i) * PADV + lr] = (unsigned short)v[i];
    if (lane < 32) {
      bf16x8 v2 = *(const bf16x8*)(qkv + rowbase + 768 + 32 + lg * 8);
#pragma unroll
      for (int i = 0; i < 8; ++i) Vt[((4 + lg) * 8 + i) * PADV + lr] = (unsigned short)v2[i];
    }
  }

  f32x4 s = {0.f, 0.f, 0.f, 0.f};
  s = __builtin_amdgcn_mfma_f32_16x16x32_bf16(aq0, bk0, s, 0, 0, 0);
  s = __builtin_amdgcn_mfma_f32_16x16x32_bf16(aq1, bk1, s, 0, 0, 0);

  const float scale = 0.14433756729740643f;  // 1/sqrt(48)
  float p[4];
#pragma unroll
  for (int r = 0; r < 4; ++r) {
    float x = s[r] * scale;
    float m = x;
    m = fmaxf(m, __shfl_xor(m, 1));
    m = fmaxf(m, __shfl_xor(m, 2));
    m = fmaxf(m, __shfl_xor(m, 4));
    m = fmaxf(m, __shfl_xor(m, 8));
    float e = __expf(x - m);
    float t = e;
    t += __shfl_xor(t, 1);
    t += __shfl_xor(t, 2);
    t += __shfl_xor(t, 4);
    t += __shfl_xor(t, 8);
    p[r] = e / t;
  }
#pragma unroll
  for (int r = 0; r < 4; ++r) P[(lg * 4 + r) * PADP + lr] = f2bf(p[r]);

  __syncthreads();

  bf16x8 ap = {0, 0, 0, 0, 0, 0, 0, 0};
  if (lg < 2) ap = *(const bf16x8*)(P + lr * PADP + lg * 8);

  f32x4 o[3];
#pragma unroll
  for (int c = 0; c < 3; ++c) {
    bf16x8 bv = {0, 0, 0, 0, 0, 0, 0, 0};
    if (lg < 2) bv = *(const bf16x8*)(Vt + (c * 16 + lr) * PADV + lg * 8);
    f32x4 z = {0.f, 0.f, 0.f, 0.f};
    o[c] = __builtin_amdgcn_mfma_f32_16x16x32_bf16(ap, bv, z, 0, 0, 0);
  }

#pragma unroll
  for (int r = 0; r < 4; ++r) {
    const int qi = lg * 4 + r;
    const int nq = (wy * 4 + (qi >> 2)) * 128 + wx * 4 + (qi & 3);
    const size_t obase = ((size_t)(b * 16384 + nq)) * 384 + h * 48;
#pragma unroll
    for (int c = 0; c < 3; ++c)
      aout[obase + c * 16 + lr] = f2bf(o[c][r]);
  }
}

// ---------------- launch ----------------
extern "C" void kernel_launch(void* const* d_in, const int* in_sizes, int n_in,
                              void* d_out, int out_size, void* d_ws, size_t ws_size,
                              hipStream_t stream) {
  const float* x      = (const float*)d_in[0];
  const float* W_qkv  = (const float*)d_in[1];
  const float* W_proj = (const float*)d_in[2];
  const float* b_proj = (const float*)d_in[3];
  float* out = (float*)d_out;

  const int Bb = 8, Nn = 16384, Cc = 384;
  const int M = Bb * Nn;       // 131072
  const int threeC = 3 * Cc;   // 1152

  char* ws = (char*)d_ws;
  unsigned short* qkv_bf  = (unsigned short*)ws;                                   // M*1152 bf16
  unsigned short* xa_bf   = (unsigned short*)(ws + (size_t)M * threeC * 2);        // M*384  bf16
  unsigned short* wqkv_bf = (unsigned short*)(ws + (size_t)M * threeC * 2 + (size_t)M * Cc * 2);
  unsigned short* wproj_bf = wqkv_bf + threeC * Cc;

  conv_f32_bf16<<<2048, 256, 0, stream>>>((const float4*)x, (ushort4*)xa_bf, M * Cc / 4);
  conv_f32_bf16<<<432, 256, 0, stream>>>((const float4*)W_qkv, (ushort4*)wqkv_bf, threeC * Cc / 4);
  conv_f32_bf16<<<144, 256, 0, stream>>>((const float4*)W_proj, (ushort4*)wproj_bf, Cc * Cc / 4);

  // qkv = x @ W_qkv^T (bf16 out): grid = 1024 m-tiles x 6 n-bands = 6144 (%8==0)
  gemm_bt<0><<<(M / 128) * (threeC / 192), 256, 0, stream>>>(xa_bf, wqkv_bf, qkv_bf, nullptr,
                                                             M, threeC, Cc);

  win_attn<<<Bb * 8 * 1024 / 4, 256, 0, stream>>>(qkv_bf, xa_bf);

  // out = attn @ W_proj^T + b (fp32 out): grid = 1024 x 2 = 2048 (%8==0)
  gemm_bt<1><<<(M / 128) * (Cc / 192), 256, 0, stream>>>(xa_bf, wproj_bf, out, b_proj,
                                                         M, Cc, Cc);
}

// Round 10
// 430.749 us; speedup vs baseline: 1.0314x; 1.0314x over previous
//
#include <hip/hip_runtime.h>
#include <hip/hip_bf16.h>
#include <cstdint>

#define ASPACE(n) __attribute__((address_space(n)))

typedef short bf16x8 __attribute__((ext_vector_type(8)));
typedef float f32x4 __attribute__((ext_vector_type(4)));

__device__ __forceinline__ unsigned short f2bf(float f) {
  uint32_t u = __float_as_uint(f);
  u += 0x7fffu + ((u >> 16) & 1u);
  return (unsigned short)(u >> 16);
}
__device__ __forceinline__ float bf2f(unsigned short h) {
  return __uint_as_float(((uint32_t)h) << 16);
}

// pack 8 fp32 -> bf16x8 via v_cvt_pk_bf16_f32 (RNE; T12 recipe, lo=src0 hi=src1)
__device__ __forceinline__ bf16x8 cvt8(float4 a, float4 b) {
  union { uint32_t u[4]; bf16x8 v; } r;
  asm("v_cvt_pk_bf16_f32 %0, %1, %2" : "=v"(r.u[0]) : "v"(a.x), "v"(a.y));
  asm("v_cvt_pk_bf16_f32 %0, %1, %2" : "=v"(r.u[1]) : "v"(a.z), "v"(a.w));
  asm("v_cvt_pk_bf16_f32 %0, %1, %2" : "=v"(r.u[2]) : "v"(b.x), "v"(b.y));
  asm("v_cvt_pk_bf16_f32 %0, %1, %2" : "=v"(r.u[3]) : "v"(b.z), "v"(b.w));
  return r.v;
}

// ---------------- fp32 -> bf16 conversion (weights only now) ----------------
__global__ __launch_bounds__(256) void conv_f32_bf16(const float4* __restrict__ src,
                                                     ushort4* __restrict__ dst, int n4) {
  int i = blockIdx.x * blockDim.x + threadIdx.x;
  int stride = gridDim.x * blockDim.x;
  for (; i < n4; i += stride) {
    float4 v = src[i];
    ushort4 o;
    o.x = f2bf(v.x); o.y = f2bf(v.y); o.z = f2bf(v.z); o.w = f2bf(v.w);
    dst[i] = o;
  }
}

__device__ __forceinline__ void gload16(const unsigned short* g, unsigned short* l) {
  __builtin_amdgcn_global_load_lds((const ASPACE(1) void*)g, (ASPACE(3) void*)l, 16, 0, 0);
}

// ============ FUSED qkv-GEMM + windowed attention ============
// Block = 128 tokens (4 y-strips x 32 x = 8 complete 4x4 windows) x 1 head.
// GEMM: [128 x 144] = x[128x384] @ Wslice^T; B dbuf in LDS (BK=32, swizzled);
// A direct-from-global fp32 + cvt_pk (per-wave private rows). qkv -> LDS only.
// Attention: proven win_attn wave-code, 2 windows/wave, qkv read from LDS.
// LDS: Bs dbuf 18 KiB | qkv 36 KiB; attn scratch aliases Bs. 54 KiB -> 2 blk/CU.
__global__ __launch_bounds__(256, 2) void fused_qkv_attn(const float* __restrict__ x,
                                                         const unsigned short* __restrict__ Wq,
                                                         unsigned short* __restrict__ aout) {
  __shared__ unsigned short lds[9216 + 18432];
  unsigned short* Bs  = lds;           // [2][4608] shorts (144x32 per buf)
  unsigned short* qkv = lds + 9216;    // [128][144] shorts
  unsigned short* scratch = lds;       // aliased after GEMM (needs 6144 shorts)

  const int tid = threadIdx.x, lane = tid & 63, wave = tid >> 6;
  const int nwg = gridDim.x;                                  // 8192, %8==0
  const int swz = (blockIdx.x & 7) * (nwg >> 3) + (blockIdx.x >> 3);
  const int h  = swz & 7;                                     // head fastest
  const int tg = swz >> 3;
  const int b = tg >> 7, yb = (tg >> 2) & 31, xb = tg & 3;
  const int tokbase = b * 16384 + (yb * 4) * 128 + xb * 32;   // + strip*128 + xx

  // ---- B staging setup: 576 chunks = [row 0..143][phys chunk 0..3], swizzled ----
  // wrow(r) = (r/48)*384 + h*48 + (r%48)
  const int c0 = tid,        r0 = c0 >> 2;
  const int c1 = 256 + tid,  r1 = c1 >> 2;
  const int c2 = 512 + lane, r2 = c2 >> 2;                    // wave 0 only issues
  const int gc0 = (c0 & 3) ^ ((r0 >> 1) & 3);
  const int gc1 = (c1 & 3) ^ ((r1 >> 1) & 3);
  const int gc2 = (c2 & 3) ^ ((r2 >> 1) & 3);
  const unsigned short* gB0 = Wq + (size_t)((r0 / 48) * 384 + h * 48 + (r0 % 48)) * 384 + gc0 * 8;
  const unsigned short* gB1 = Wq + (size_t)((r1 / 48) * 384 + h * 48 + (r1 % 48)) * 384 + gc1 * 8;
  const unsigned short* gB2 = Wq + (size_t)((r2 / 48) * 384 + h * 48 + (r2 % 48)) * 384 + gc2 * 8;
  unsigned short* lB0 = Bs + (0 * 256 + wave * 64) * 8;
  unsigned short* lB1 = Bs + (1 * 256 + wave * 64) * 8;
  unsigned short* lB2 = Bs + 512 * 8;

  const int fr = lane & 15;
  const int hi = lane >> 4;

  // hoisted B fragment offsets (9 col-frags)
  int bfo[9];
#pragma unroll
  for (int n = 0; n < 9; ++n) {
    const int row = n * 16 + fr;
    bfo[n] = row * 32 + ((hi ^ ((row >> 1) & 3)) * 8);
  }

  // A pointers: wave = y-strip; frag-row mf=0 -> xx=fr, mf=1 -> xx=16+fr
  const float* pA0 = x + (size_t)(tokbase + wave * 128 + fr) * 384 + hi * 8;
  const float* pA1 = pA0 + (size_t)16 * 384;

  f32x4 acc[2][9];
#pragma unroll
  for (int mf = 0; mf < 2; ++mf)
#pragma unroll
    for (int n = 0; n < 9; ++n) {
      f32x4 z = {0.f, 0.f, 0.f, 0.f};
      acc[mf][n] = z;
    }

  // prologue: stage B(0) into buf0; preload A(0)
  gload16(gB0, lB0); gload16(gB1, lB1);
  if (wave == 0) gload16(gB2, lB2);
  float4 a00 = *(const float4*)(pA0);
  float4 a01 = *(const float4*)(pA0 + 4);
  float4 a10 = *(const float4*)(pA1);
  float4 a11 = *(const float4*)(pA1 + 4);
  __syncthreads();

#pragma unroll
  for (int t = 0; t < 12; ++t) {
    const int buf = t & 1;
    if (t < 11) {   // stage B(t+1) + preload A(t+1) (latency hides under compute)
      const int k0 = (t + 1) * 32;
      const int nb = (t + 1) & 1;
      gload16(gB0 + k0, lB0 + nb * 4608);
      gload16(gB1 + k0, lB1 + nb * 4608);
      if (wave == 0) gload16(gB2 + k0, lB2 + nb * 4608);
    }
    bf16x8 af0 = cvt8(a00, a01);
    bf16x8 af1 = cvt8(a10, a11);
    if (t < 11) {
      const int ko = (t + 1) * 32;
      a00 = *(const float4*)(pA0 + ko);
      a01 = *(const float4*)(pA0 + ko + 4);
      a10 = *(const float4*)(pA1 + ko);
      a11 = *(const float4*)(pA1 + ko + 4);
    }
    const unsigned short* Bb = Bs + buf * 4608;
    bf16x8 bfv[9];
#pragma unroll
    for (int n = 0; n < 9; ++n) bfv[n] = *(const bf16x8*)(Bb + bfo[n]);
#pragma unroll
    for (int n = 0; n < 9; ++n) {
      acc[0][n] = __builtin_amdgcn_mfma_f32_16x16x32_bf16(af0, bfv[n], acc[0][n], 0, 0, 0);
      acc[1][n] = __builtin_amdgcn_mfma_f32_16x16x32_bf16(af1, bfv[n], acc[1][n], 0, 0, 0);
    }
    __syncthreads();
  }

  // ---- acc -> qkv LDS: token = 32*wave + 16*mf + hi*4 + r, col = n*16 + fr ----
  {
    unsigned short* qb = qkv + (32 * wave + hi * 4) * 144 + fr;
#pragma unroll
    for (int mf = 0; mf < 2; ++mf)
#pragma unroll
      for (int n = 0; n < 9; ++n)
#pragma unroll
        for (int r = 0; r < 4; ++r)
          qb[(16 * mf + r) * 144 + n * 16] = f2bf(acc[mf][n][r]);
  }
  __syncthreads();   // qkv visible to all waves; Bs reads done -> scratch reusable

  // ---- attention: 2 windows per wave (proven win_attn wave code, LDS source) ----
  unsigned short* Vt = scratch + wave * 1536;   // [48][24]
  unsigned short* P  = Vt + 48 * 24;            // [16][24]
  const int lg = hi;  // lane>>4
  const int lr = fr;  // lane&15

  for (int wi = 0; wi < 2; ++wi) {
    const int wxl = wave * 2 + wi;                            // window 0..7
    const int btok = (lr >> 2) * 32 + wxl * 4 + (lr & 3);     // block-token of window-row lr
    const unsigned short* qrow = qkv + btok * 144;

    bf16x8 aq0 = *(const bf16x8*)(qrow + lg * 8);             // q cols 0..31
    bf16x8 bk0 = *(const bf16x8*)(qrow + 48 + lg * 8);        // k cols 0..31
    bf16x8 aq1 = {0, 0, 0, 0, 0, 0, 0, 0};
    bf16x8 bk1 = {0, 0, 0, 0, 0, 0, 0, 0};
    if (lg < 2) {
      aq1 = *(const bf16x8*)(qrow + 32 + lg * 8);             // q cols 32..47
      bk1 = *(const bf16x8*)(qrow + 80 + lg * 8);             // k cols 32..47
    }
    {
      bf16x8 v = *(const bf16x8*)(qrow + 96 + lg * 8);        // v dims lg*8..+8
#pragma unroll
      for (int i = 0; i < 8; ++i) Vt[(lg * 8 + i) * 24 + lr] = (unsigned short)v[i];
      if (lane < 32) {
        bf16x8 v2 = *(const bf16x8*)(qrow + 128 + lg * 8);    // v dims 32..47
#pragma unroll
        for (int i = 0; i < 8; ++i) Vt[((4 + lg) * 8 + i) * 24 + lr] = (unsigned short)v2[i];
      }
    }

    f32x4 s = {0.f, 0.f, 0.f, 0.f};
    s = __builtin_amdgcn_mfma_f32_16x16x32_bf16(aq0, bk0, s, 0, 0, 0);
    s = __builtin_amdgcn_mfma_f32_16x16x32_bf16(aq1, bk1, s, 0, 0, 0);

    const float scale = 0.14433756729740643f;  // 1/sqrt(48)
    float p[4];
#pragma unroll
    for (int r = 0; r < 4; ++r) {
      float xv = s[r] * scale;
      float m = xv;
      m = fmaxf(m, __shfl_xor(m, 1));
      m = fmaxf(m, __shfl_xor(m, 2));
      m = fmaxf(m, __shfl_xor(m, 4));
      m = fmaxf(m, __shfl_xor(m, 8));
      float e = __expf(xv - m);
      float tt = e;
      tt += __shfl_xor(tt, 1);
      tt += __shfl_xor(tt, 2);
      tt += __shfl_xor(tt, 4);
      tt += __shfl_xor(tt, 8);
      p[r] = e / tt;
    }
#pragma unroll
    for (int r = 0; r < 4; ++r) P[(lg * 4 + r) * 24 + lr] = f2bf(p[r]);

    __syncthreads();   // order Vt/P writes before fragment reads (uniform)

    bf16x8 ap = {0, 0, 0, 0, 0, 0, 0, 0};
    if (lg < 2) ap = *(const bf16x8*)(P + lr * 24 + lg * 8);

    f32x4 o[3];
#pragma unroll
    for (int c = 0; c < 3; ++c) {
      bf16x8 bv = {0, 0, 0, 0, 0, 0, 0, 0};
      if (lg < 2) bv = *(const bf16x8*)(Vt + (c * 16 + lr) * 24 + lg * 8);
      f32x4 z = {0.f, 0.f, 0.f, 0.f};
      o[c] = __builtin_amdgcn_mfma_f32_16x16x32_bf16(ap, bv, z, 0, 0, 0);
    }

#pragma unroll
    for (int r = 0; r < 4; ++r) {
      const int qi = lg * 4 + r;
      const int g = tokbase + (qi >> 2) * 128 + wxl * 4 + (qi & 3);
      unsigned short* ob = aout + (size_t)g * 384 + h * 48;
#pragma unroll
      for (int c = 0; c < 3; ++c) ob[c * 16 + lr] = f2bf(o[c][r]);
    }
    __syncthreads();   // Vt/P safe to overwrite next wi (uniform)
  }
}

// ---------------- proj GEMM (r7-proven kernel, verbatim) ----------------
template <int OUT_MODE>
__global__ __launch_bounds__(256, 3) void gemm_bt(const unsigned short* __restrict__ A,
                                                  const unsigned short* __restrict__ B,
                                                  void* __restrict__ Cout,
                                                  const float* __restrict__ bias,
                                                  int M, int N, int K) {
  __shared__ unsigned short As[2][128 * 32];
  __shared__ unsigned short Bs[2][192 * 32];

  const int tid  = threadIdx.x;
  const int lane = tid & 63;
  const int wave = tid >> 6;
  const int wr = wave >> 1;
  const int wc = wave & 1;

  const int nwg = gridDim.x;
  const int swz = (blockIdx.x & 7) * (nwg >> 3) + (blockIdx.x >> 3);
  const int ntn = N / 192;
  const int bn0 = (swz % ntn) * 192;
  const int bm0 = (swz / ntn) << 7;

  const unsigned short* Abase = A + (size_t)bm0 * K;
  const unsigned short* Bbase = B + (size_t)bn0 * K;

  const unsigned short* gA[2];
  const unsigned short* gB[3];
  unsigned short* lA[2];
  unsigned short* lB[3];
#pragma unroll
  for (int i = 0; i < 2; ++i) {
    const int c = i * 256 + tid;
    const int r = c >> 2;
    const int gc = (c & 3) ^ ((r >> 1) & 3);
    gA[i] = Abase + (size_t)r * K + gc * 8;
    lA[i] = (unsigned short*)As + (i * 256 + wave * 64) * 8;
  }
#pragma unroll
  for (int i = 0; i < 3; ++i) {
    const int c = i * 256 + tid;
    const int r = c >> 2;
    const int gc = (c & 3) ^ ((r >> 1) & 3);
    gB[i] = Bbase + (size_t)r * K + gc * 8;
    lB[i] = (unsigned short*)Bs + (i * 256 + wave * 64) * 8;
  }
  const int abufoff = 128 * 32;
  const int bbufoff = 192 * 32;

  const int fr = lane & 15;
  const int hi = lane >> 4;
  int afo[4], bfo[6];
#pragma unroll
  for (int m = 0; m < 4; ++m) {
    const int row = wr * 64 + m * 16 + fr;
    afo[m] = row * 32 + ((hi ^ ((row >> 1) & 3)) * 8);
  }
#pragma unroll
  for (int n = 0; n < 6; ++n) {
    const int row = wc * 96 + n * 16 + fr;
    bfo[n] = row * 32 + ((hi ^ ((row >> 1) & 3)) * 8);
  }

  f32x4 acc[4][6];
#pragma unroll
  for (int m = 0; m < 4; ++m)
#pragma unroll
    for (int n = 0; n < 6; ++n) {
      f32x4 z = {0.f, 0.f, 0.f, 0.f};
      acc[m][n] = z;
    }

  const int NT = K >> 5;

#pragma unroll
  for (int i = 0; i < 2; ++i) gload16(gA[i], lA[i]);
#pragma unroll
  for (int i = 0; i < 3; ++i) gload16(gB[i], lB[i]);
  __syncthreads();

  int cur = 0;
  for (int t = 0; t < NT; ++t) {
    if (t + 1 < NT) {
      const int nb = cur ^ 1;
      const int k0 = (t + 1) << 5;
#pragma unroll
      for (int i = 0; i < 2; ++i) gload16(gA[i] + k0, lA[i] + nb * abufoff);
#pragma unroll
      for (int i = 0; i < 3; ++i) gload16(gB[i] + k0, lB[i] + nb * bbufoff);
    }
    {
      const unsigned short* Ab = (const unsigned short*)As + cur * abufoff;
      const unsigned short* Bb = (const unsigned short*)Bs + cur * bbufoff;
      bf16x8 af[4], bfv[6];
#pragma unroll
      for (int m = 0; m < 4; ++m) af[m] = *(const bf16x8*)(Ab + afo[m]);
#pragma unroll
      for (int n = 0; n < 6; ++n) bfv[n] = *(const bf16x8*)(Bb + bfo[n]);
#pragma unroll
      for (int m = 0; m < 4; ++m)
#pragma unroll
        for (int n = 0; n < 6; ++n)
          acc[m][n] = __builtin_amdgcn_mfma_f32_16x16x32_bf16(af[m], bfv[n], acc[m][n], 0, 0, 0);
    }
    __syncthreads();
    cur ^= 1;
  }

  const int rq = hi * 4;
  if (OUT_MODE == 1) {
    float* C = (float*)Cout;
#pragma unroll
    for (int m = 0; m < 4; ++m) {
#pragma unroll
      for (int n = 0; n < 6; ++n) {
        const int col = bn0 + wc * 96 + n * 16 + fr;
        const float bv = bias[col];
#pragma unroll
        for (int r = 0; r < 4; ++r) {
          const int row = bm0 + wr * 64 + m * 16 + rq + r;
          C[(size_t)row * N + col] = acc[m][n][r] + bv;
        }
      }
    }
  } else {
    unsigned short* C = (unsigned short*)Cout;
#pragma unroll
    for (int m = 0; m < 4; ++m) {
#pragma unroll
      for (int n = 0; n < 6; ++n) {
        const int col = bn0 + wc * 96 + n * 16 + fr;
#pragma unroll
        for (int r = 0; r < 4; ++r) {
          const int row = bm0 + wr * 64 + m * 16 + rq + r;
          C[(size_t)row * N + col] = f2bf(acc[m][n][r]);
        }
      }
    }
  }
}

// ---------------- launch ----------------
extern "C" void kernel_launch(void* const* d_in, const int* in_sizes, int n_in,
                              void* d_out, int out_size, void* d_ws, size_t ws_size,
                              hipStream_t stream) {
  const float* x      = (const float*)d_in[0];
  const float* W_qkv  = (const float*)d_in[1];
  const float* W_proj = (const float*)d_in[2];
  const float* b_proj = (const float*)d_in[3];
  float* out = (float*)d_out;

  const int Bb = 8, Nn = 16384, Cc = 384;
  const int M = Bb * Nn;       // 131072
  const int threeC = 3 * Cc;   // 1152

  char* ws = (char*)d_ws;
  unsigned short* xa_bf    = (unsigned short*)ws;                        // M*384 bf16 (attn out)
  unsigned short* wqkv_bf  = (unsigned short*)(ws + (size_t)M * Cc * 2);
  unsigned short* wproj_bf = wqkv_bf + threeC * Cc;

  // weight conversions (tiny)
  conv_f32_bf16<<<432, 256, 0, stream>>>((const float4*)W_qkv, (ushort4*)wqkv_bf,
                                         threeC * Cc / 4);
  conv_f32_bf16<<<144, 256, 0, stream>>>((const float4*)W_proj, (ushort4*)wproj_bf,
                                         Cc * Cc / 4);

  // fused qkv GEMM + windowed attention: 1024 token-groups x 8 heads
  fused_qkv_attn<<<8192, 256, 0, stream>>>(x, wqkv_bf, xa_bf);

  // out = attn @ W_proj^T + b (fp32): grid = 1024 x 2 = 2048 (%8==0)
  gemm_bt<1><<<(M / 128) * (Cc / 192), 256, 0, stream>>>(xa_bf, wproj_bf, out, b_proj,
                                                         M, Cc, Cc);
}

// Round 12
// 427.178 us; speedup vs baseline: 1.0401x; 1.0084x over previous
//
#include <hip/hip_runtime.h>
#include <hip/hip_bf16.h>
#include <cstdint>

#define ASPACE(n) __attribute__((address_space(n)))

typedef short bf16x8 __attribute__((ext_vector_type(8)));
typedef float f32x4 __attribute__((ext_vector_type(4)));

__device__ __forceinline__ unsigned short f2bf(float f) {
  uint32_t u = __float_as_uint(f);
  u += 0x7fffu + ((u >> 16) & 1u);
  return (unsigned short)(u >> 16);
}
__device__ __forceinline__ float bf2f(unsigned short h) {
  return __uint_as_float(((uint32_t)h) << 16);
}

// pack 8 fp32 -> bf16x8 via v_cvt_pk_bf16_f32 (RNE)
__device__ __forceinline__ bf16x8 cvt8(float4 a, float4 b) {
  union { uint32_t u[4]; bf16x8 v; } r;
  asm("v_cvt_pk_bf16_f32 %0, %1, %2" : "=v"(r.u[0]) : "v"(a.x), "v"(a.y));
  asm("v_cvt_pk_bf16_f32 %0, %1, %2" : "=v"(r.u[1]) : "v"(a.z), "v"(a.w));
  asm("v_cvt_pk_bf16_f32 %0, %1, %2" : "=v"(r.u[2]) : "v"(b.x), "v"(b.y));
  asm("v_cvt_pk_bf16_f32 %0, %1, %2" : "=v"(r.u[3]) : "v"(b.z), "v"(b.w));
  return r.v;
}

// ---------------- fp32 -> bf16 conversion (weights only) ----------------
__global__ __launch_bounds__(256) void conv_f32_bf16(const float4* __restrict__ src,
                                                     ushort4* __restrict__ dst, int n4) {
  int i = blockIdx.x * blockDim.x + threadIdx.x;
  int stride = gridDim.x * blockDim.x;
  for (; i < n4; i += stride) {
    float4 v = src[i];
    ushort4 o;
    o.x = f2bf(v.x); o.y = f2bf(v.y); o.z = f2bf(v.z); o.w = f2bf(v.w);
    dst[i] = o;
  }
}

__device__ __forceinline__ void gload16(const unsigned short* g, unsigned short* l) {
  __builtin_amdgcn_global_load_lds((const ASPACE(1) void*)g, (ASPACE(3) void*)l, 16, 0, 0);
}

// ============ FUSED qkv-GEMM + windowed attention ============
// Block = 128 tokens (4 y-strips x 32 = 8 complete 4x4 windows) x 1 head.
// GEMM loop: counted vmcnt(4) + raw s_barrier, with sched_barrier(0) fences pinning
// issue order [B gloads][A loads] so vmcnt(4) provably retires the B stages while
// the 4 A fp32 loads ride across the barrier (r8-proven fence discipline; r11's
// fence-less variant raced -- compiler hoisted A loads above B gloads).
// qkv row stride 146 (pad 2) kills the 8-way epilogue write conflict.
#define QSTR 146
__global__ __launch_bounds__(256, 2) void fused_qkv_attn(const float* __restrict__ x,
                                                         const unsigned short* __restrict__ Wq,
                                                         unsigned short* __restrict__ aout) {
  __shared__ unsigned short lds[9216 + 128 * QSTR];
  unsigned short* Bs  = lds;              // [2][4608] shorts (144x32 per buf)
  unsigned short* qkv = lds + 9216;       // [128][QSTR]
  unsigned short* scratch = lds;          // aliases Bs after GEMM (needs 6144 shorts)

  const int tid = threadIdx.x, lane = tid & 63, wave = tid >> 6;
  const int nwg = gridDim.x;              // 8192, %8==0
  const int swz = (blockIdx.x & 7) * (nwg >> 3) + (blockIdx.x >> 3);
  const int h  = swz & 7;                 // head fastest -> 8 heads of a group co-XCD
  const int tg = swz >> 3;
  const int b = tg >> 7, yb = (tg >> 2) & 31, xb = tg & 3;
  const int tokbase = b * 16384 + (yb * 4) * 128 + xb * 32;

  // ---- B staging: 576 chunks = [row 0..143][phys chunk 0..3], swizzled ----
  const int c0 = tid,        r0 = c0 >> 2;
  const int c1 = 256 + tid,  r1 = c1 >> 2;
  const int c2 = 512 + lane, r2 = c2 >> 2;       // wave 0 only
  const int gc0 = (c0 & 3) ^ ((r0 >> 1) & 3);
  const int gc1 = (c1 & 3) ^ ((r1 >> 1) & 3);
  const int gc2 = (c2 & 3) ^ ((r2 >> 1) & 3);
  const unsigned short* gB0 = Wq + (size_t)((r0 / 48) * 384 + h * 48 + (r0 % 48)) * 384 + gc0 * 8;
  const unsigned short* gB1 = Wq + (size_t)((r1 / 48) * 384 + h * 48 + (r1 % 48)) * 384 + gc1 * 8;
  const unsigned short* gB2 = Wq + (size_t)((r2 / 48) * 384 + h * 48 + (r2 % 48)) * 384 + gc2 * 8;
  unsigned short* lB0 = Bs + (0 * 256 + wave * 64) * 8;
  unsigned short* lB1 = Bs + (1 * 256 + wave * 64) * 8;
  unsigned short* lB2 = Bs + 512 * 8;

  const int fr = lane & 15;
  const int hi = lane >> 4;

  int bfo[9];
#pragma unroll
  for (int n = 0; n < 9; ++n) {
    const int row = n * 16 + fr;
    bfo[n] = row * 32 + ((hi ^ ((row >> 1) & 3)) * 8);
  }

  // A pointers: wave = y-strip; frag rows fr and 16+fr
  const float* pA0 = x + (size_t)(tokbase + wave * 128 + fr) * 384 + hi * 8;
  const float* pA1 = pA0 + (size_t)16 * 384;

  f32x4 acc[2][9];
#pragma unroll
  for (int mf = 0; mf < 2; ++mf)
#pragma unroll
    for (int n = 0; n < 9; ++n) {
      f32x4 z = {0.f, 0.f, 0.f, 0.f};
      acc[mf][n] = z;
    }

  // prologue: B(0) gloads FIRST, fence, then A(0) preloads; vmcnt(4) retires B only
  gload16(gB0, lB0); gload16(gB1, lB1);
  if (wave == 0) gload16(gB2, lB2);
  __builtin_amdgcn_sched_barrier(0);
  float4 a00 = *(const float4*)(pA0);
  float4 a01 = *(const float4*)(pA0 + 4);
  float4 a10 = *(const float4*)(pA1);
  float4 a11 = *(const float4*)(pA1 + 4);
  asm volatile("s_waitcnt vmcnt(4)" ::: "memory");
  __builtin_amdgcn_s_barrier();
  __builtin_amdgcn_sched_barrier(0);

#pragma unroll
  for (int t = 0; t < 12; ++t) {
    const int buf = t & 1;
    if (t < 11) {                        // issue B(t+1) stage first (pinned by fence)
      const int k0 = (t + 1) * 32;
      const int nb = (t + 1) & 1;
      gload16(gB0 + k0, lB0 + nb * 4608);
      gload16(gB1 + k0, lB1 + nb * 4608);
      if (wave == 0) gload16(gB2 + k0, lB2 + nb * 4608);
    }
    __builtin_amdgcn_sched_barrier(0);   // B gloads precede A loads in issue order
    bf16x8 af0 = cvt8(a00, a01);         // compiler vmcnt-waits A(t)
    bf16x8 af1 = cvt8(a10, a11);
    if (t < 11) {                        // preload A(t+1) (rides across the barrier)
      const int ko = (t + 1) * 32;
      a00 = *(const float4*)(pA0 + ko);
      a01 = *(const float4*)(pA0 + ko + 4);
      a10 = *(const float4*)(pA1 + ko);
      a11 = *(const float4*)(pA1 + ko + 4);
    }
    const unsigned short* Bb = Bs + buf * 4608;
    bf16x8 bfv[9];
#pragma unroll
    for (int n = 0; n < 9; ++n) bfv[n] = *(const bf16x8*)(Bb + bfo[n]);
#pragma unroll
    for (int n = 0; n < 9; ++n) {
      acc[0][n] = __builtin_amdgcn_mfma_f32_16x16x32_bf16(af0, bfv[n], acc[0][n], 0, 0, 0);
      acc[1][n] = __builtin_amdgcn_mfma_f32_16x16x32_bf16(af1, bfv[n], acc[1][n], 0, 0, 0);
    }
    if (t < 11) {
      // retire B(t+1) (oldest); A(t+1) 4 loads stay in flight across the barrier
      asm volatile("s_waitcnt vmcnt(4)" ::: "memory");
      __builtin_amdgcn_s_barrier();
      __builtin_amdgcn_sched_barrier(0);
    }
  }

  // ---- acc -> qkv LDS (row stride QSTR=146: bank 73*tok, odd -> spread) ----
  {
    unsigned short* qb = qkv + (32 * wave + hi * 4) * QSTR + fr;
#pragma unroll
    for (int mf = 0; mf < 2; ++mf)
#pragma unroll
      for (int n = 0; n < 9; ++n)
#pragma unroll
        for (int r = 0; r < 4; ++r)
          qb[(16 * mf + r) * QSTR + n * 16] = f2bf(acc[mf][n][r]);
  }
  __syncthreads();   // qkv published; Bs reads done -> scratch reusable

  // ---- attention: 2 windows per wave (r10-proven, barriers restored) ----
  unsigned short* Vt = scratch + wave * 1536;   // [48][24]
  unsigned short* P  = Vt + 48 * 24;            // [16][24]
  const int lg = hi;
  const int lr = fr;

  for (int wi = 0; wi < 2; ++wi) {
    const int wxl = wave * 2 + wi;                            // window 0..7
    const int btok = (lr >> 2) * 32 + wxl * 4 + (lr & 3);     // block-token of window-row lr
    const unsigned short* qrow = qkv + btok * QSTR;

    bf16x8 aq0 = *(const bf16x8*)(qrow + lg * 8);
    bf16x8 bk0 = *(const bf16x8*)(qrow + 48 + lg * 8);
    bf16x8 aq1 = {0, 0, 0, 0, 0, 0, 0, 0};
    bf16x8 bk1 = {0, 0, 0, 0, 0, 0, 0, 0};
    if (lg < 2) {
      aq1 = *(const bf16x8*)(qrow + 32 + lg * 8);
      bk1 = *(const bf16x8*)(qrow + 80 + lg * 8);
    }
    {
      bf16x8 v = *(const bf16x8*)(qrow + 96 + lg * 8);
#pragma unroll
      for (int i = 0; i < 8; ++i) Vt[(lg * 8 + i) * 24 + lr] = (unsigned short)v[i];
      if (lane < 32) {
        bf16x8 v2 = *(const bf16x8*)(qrow + 128 + lg * 8);
#pragma unroll
        for (int i = 0; i < 8; ++i) Vt[((4 + lg) * 8 + i) * 24 + lr] = (unsigned short)v2[i];
      }
    }

    f32x4 s = {0.f, 0.f, 0.f, 0.f};
    s = __builtin_amdgcn_mfma_f32_16x16x32_bf16(aq0, bk0, s, 0, 0, 0);
    s = __builtin_amdgcn_mfma_f32_16x16x32_bf16(aq1, bk1, s, 0, 0, 0);

    const float scale = 0.14433756729740643f;  // 1/sqrt(48)
    float p[4];
#pragma unroll
    for (int r = 0; r < 4; ++r) {
      float xv = s[r] * scale;
      float m = xv;
      m = fmaxf(m, __shfl_xor(m, 1));
      m = fmaxf(m, __shfl_xor(m, 2));
      m = fmaxf(m, __shfl_xor(m, 4));
      m = fmaxf(m, __shfl_xor(m, 8));
      float e = __expf(xv - m);
      float tt = e;
      tt += __shfl_xor(tt, 1);
      tt += __shfl_xor(tt, 2);
      tt += __shfl_xor(tt, 4);
      tt += __shfl_xor(tt, 8);
      p[r] = e / tt;
    }
#pragma unroll
    for (int r = 0; r < 4; ++r) P[(lg * 4 + r) * 24 + lr] = f2bf(p[r]);

    __syncthreads();   // order Vt/P writes before fragment reads (uniform)

    bf16x8 ap = {0, 0, 0, 0, 0, 0, 0, 0};
    if (lg < 2) ap = *(const bf16x8*)(P + lr * 24 + lg * 8);

    f32x4 o[3];
#pragma unroll
    for (int c = 0; c < 3; ++c) {
      bf16x8 bv = {0, 0, 0, 0, 0, 0, 0, 0};
      if (lg < 2) bv = *(const bf16x8*)(Vt + (c * 16 + lr) * 24 + lg * 8);
      f32x4 z = {0.f, 0.f, 0.f, 0.f};
      o[c] = __builtin_amdgcn_mfma_f32_16x16x32_bf16(ap, bv, z, 0, 0, 0);
    }

#pragma unroll
    for (int r = 0; r < 4; ++r) {
      const int qi = lg * 4 + r;
      const int g = tokbase + (qi >> 2) * 128 + wxl * 4 + (qi & 3);
      unsigned short* ob = aout + (size_t)g * 384 + h * 48;
#pragma unroll
      for (int c = 0; c < 3; ++c) ob[c * 16 + lr] = f2bf(o[c][r]);
    }
    __syncthreads();   // Vt/P safe to overwrite next wi (uniform)
  }
}

// ---------------- proj GEMM (r7-proven kernel, verbatim) ----------------
template <int OUT_MODE>
__global__ __launch_bounds__(256, 3) void gemm_bt(const unsigned short* __restrict__ A,
                                                  const unsigned short* __restrict__ B,
                                                  void* __restrict__ Cout,
                                                  const float* __restrict__ bias,
                                                  int M, int N, int K) {
  __shared__ unsigned short As[2][128 * 32];
  __shared__ unsigned short Bs[2][192 * 32];

  const int tid  = threadIdx.x;
  const int lane = tid & 63;
  const int wave = tid >> 6;
  const int wr = wave >> 1;
  const int wc = wave & 1;

  const int nwg = gridDim.x;
  const int swz = (blockIdx.x & 7) * (nwg >> 3) + (blockIdx.x >> 3);
  const int ntn = N / 192;
  const int bn0 = (swz % ntn) * 192;
  const int bm0 = (swz / ntn) << 7;

  const unsigned short* Abase = A + (size_t)bm0 * K;
  const unsigned short* Bbase = B + (size_t)bn0 * K;

  const unsigned short* gA[2];
  const unsigned short* gB[3];
  unsigned short* lA[2];
  unsigned short* lB[3];
#pragma unroll
  for (int i = 0; i < 2; ++i) {
    const int c = i * 256 + tid;
    const int r = c >> 2;
    const int gc = (c & 3) ^ ((r >> 1) & 3);
    gA[i] = Abase + (size_t)r * K + gc * 8;
    lA[i] = (unsigned short*)As + (i * 256 + wave * 64) * 8;
  }
#pragma unroll
  for (int i = 0; i < 3; ++i) {
    const int c = i * 256 + tid;
    const int r = c >> 2;
    const int gc = (c & 3) ^ ((r >> 1) & 3);
    gB[i] = Bbase + (size_t)r * K + gc * 8;
    lB[i] = (unsigned short*)Bs + (i * 256 + wave * 64) * 8;
  }
  const int abufoff = 128 * 32;
  const int bbufoff = 192 * 32;

  const int fr = lane & 15;
  const int hi = lane >> 4;
  int afo[4], bfo[6];
#pragma unroll
  for (int m = 0; m < 4; ++m) {
    const int row = wr * 64 + m * 16 + fr;
    afo[m] = row * 32 + ((hi ^ ((row >> 1) & 3)) * 8);
  }
#pragma unroll
  for (int n = 0; n < 6; ++n) {
    const int row = wc * 96 + n * 16 + fr;
    bfo[n] = row * 32 + ((hi ^ ((row >> 1) & 3)) * 8);
  }

  f32x4 acc[4][6];
#pragma unroll
  for (int m = 0; m < 4; ++m)
#pragma unroll
    for (int n = 0; n < 6; ++n) {
      f32x4 z = {0.f, 0.f, 0.f, 0.f};
      acc[m][n] = z;
    }

  const int NT = K >> 5;

#pragma unroll
  for (int i = 0; i < 2; ++i) gload16(gA[i], lA[i]);
#pragma unroll
  for (int i = 0; i < 3; ++i) gload16(gB[i], lB[i]);
  __syncthreads();

  int cur = 0;
  for (int t = 0; t < NT; ++t) {
    if (t + 1 < NT) {
      const int nb = cur ^ 1;
      const int k0 = (t + 1) << 5;
#pragma unroll
      for (int i = 0; i < 2; ++i) gload16(gA[i] + k0, lA[i] + nb * abufoff);
#pragma unroll
      for (int i = 0; i < 3; ++i) gload16(gB[i] + k0, lB[i] + nb * bbufoff);
    }
    {
      const unsigned short* Ab = (const unsigned short*)As + cur * abufoff;
      const unsigned short* Bb = (const unsigned short*)Bs + cur * bbufoff;
      bf16x8 af[4], bfv[6];
#pragma unroll
      for (int m = 0; m < 4; ++m) af[m] = *(const bf16x8*)(Ab + afo[m]);
#pragma unroll
      for (int n = 0; n < 6; ++n) bfv[n] = *(const bf16x8*)(Bb + bfo[n]);
#pragma unroll
      for (int m = 0; m < 4; ++m)
#pragma unroll
        for (int n = 0; n < 6; ++n)
          acc[m][n] = __builtin_amdgcn_mfma_f32_16x16x32_bf16(af[m], bfv[n], acc[m][n], 0, 0, 0);
    }
    __syncthreads();
    cur ^= 1;
  }

  const int rq = hi * 4;
  if (OUT_MODE == 1) {
    float* C = (float*)Cout;
#pragma unroll
    for (int m = 0; m < 4; ++m) {
#pragma unroll
      for (int n = 0; n < 6; ++n) {
        const int col = bn0 + wc * 96 + n * 16 + fr;
        const float bv = bias[col];
#pragma unroll
        for (int r = 0; r < 4; ++r) {
          const int row = bm0 + wr * 64 + m * 16 + rq + r;
          C[(size_t)row * N + col] = acc[m][n][r] + bv;
        }
      }
    }
  } else {
    unsigned short* C = (unsigned short*)Cout;
#pragma unroll
    for (int m = 0; m < 4; ++m) {
#pragma unroll
      for (int n = 0; n < 6; ++n) {
        const int col = bn0 + wc * 96 + n * 16 + fr;
#pragma unroll
        for (int r = 0; r < 4; ++r) {
          const int row = bm0 + wr * 64 + m * 16 + rq + r;
          C[(size_t)row * N + col] = f2bf(acc[m][n][r]);
        }
      }
    }
  }
}

// ---------------- launch ----------------
extern "C" void kernel_launch(void* const* d_in, const int* in_sizes, int n_in,
                              void* d_out, int out_size, void* d_ws, size_t ws_size,
                              hipStream_t stream) {
  const float* x      = (const float*)d_in[0];
  const float* W_qkv  = (const float*)d_in[1];
  const float* W_proj = (const float*)d_in[2];
  const float* b_proj = (const float*)d_in[3];
  float* out = (float*)d_out;

  const int Bb = 8, Nn = 16384, Cc = 384;
  const int M = Bb * Nn;       // 131072
  const int threeC = 3 * Cc;   // 1152

  char* ws = (char*)d_ws;
  unsigned short* xa_bf    = (unsigned short*)ws;                        // M*384 bf16 (attn out)
  unsigned short* wqkv_bf  = (unsigned short*)(ws + (size_t)M * Cc * 2);
  unsigned short* wproj_bf = wqkv_bf + threeC * Cc;

  conv_f32_bf16<<<432, 256, 0, stream>>>((const float4*)W_qkv, (ushort4*)wqkv_bf,
                                         threeC * Cc / 4);
  conv_f32_bf16<<<144, 256, 0, stream>>>((const float4*)W_proj, (ushort4*)wproj_bf,
                                         Cc * Cc / 4);

  // fused qkv GEMM + windowed attention: 1024 token-groups x 8 heads
  fused_qkv_attn<<<8192, 256, 0, stream>>>(x, wqkv_bf, xa_bf);

  // out = attn @ W_proj^T + b (fp32): grid = 1024 x 2 = 2048 (%8==0)
  gemm_bt<1><<<(M / 128) * (Cc / 192), 256, 0, stream>>>(xa_bf, wproj_bf, out, b_proj,
                                                         M, Cc, Cc);
}